// Round 1
// baseline (428.821 us; speedup 1.0000x reference)
//
#include <hip/hip_runtime.h>
#include <stdint.h>

// DreamGraphReasoner on MI355X (gfx950)
// x layout: (N, B, D) row-major, row r = n*B + b  (== input (G,L,B,D) flat order)
// Sparse attention: node n=(g,l) attends to {(g',l): g'!=g} U {(g,l+1) if l<63}

#define Gd 16
#define Ld 64
#define Bb 16
#define Dd 512
#define NN 1024   // Gd*Ld
#define MM 16384  // NN*Bb

typedef __bf16 bf16;
typedef __bf16 bf16x8 __attribute__((ext_vector_type(8)));
typedef __bf16 bf16x4 __attribute__((ext_vector_type(4)));
typedef float  f32x4  __attribute__((ext_vector_type(4)));

__device__ __forceinline__ void gload_lds16(const void* g, void* l) {
  // global -> LDS direct, 16B per lane; LDS dest is wave-uniform base + lane*16
  __builtin_amdgcn_global_load_lds(
      (__attribute__((address_space(1))) void*)(size_t)(g),
      (__attribute__((address_space(3))) void*)(l), 16, 0, 0);
}

// ---------------- weight prep: bf16 transpose (+ concat QKV bias) -------------
__global__ void prep_weights(const float* __restrict__ Wq, const float* __restrict__ Wk,
                             const float* __restrict__ Wv, const float* __restrict__ Whop,
                             const float* __restrict__ bq, const float* __restrict__ bk,
                             const float* __restrict__ bv,
                             bf16* __restrict__ WtQKV, bf16* __restrict__ WtHop,
                             float* __restrict__ bcat) {
  int t = blockIdx.x * 256 + threadIdx.x;
  if (t < 1536 * 512) {                 // WtQKV[col][k] = W*[k][col&511]
    int col = t >> 9, k = t & 511;
    const float* W = (col < 512) ? Wq : (col < 1024 ? Wk : Wv);
    WtQKV[t] = (bf16)W[k * 512 + (col & 511)];
  } else if (t < 2 * 1536 * 512) {      // WtHop[h][col][k] = Whop[h][k][col]
    int t2 = t - 1536 * 512;
    int h = t2 >> 18, rem = t2 & 262143;
    int col = rem >> 9, k = rem & 511;
    WtHop[t2] = (bf16)Whop[h * 262144 + k * 512 + col];
  } else if (t < 2 * 1536 * 512 + 1536) {
    int t3 = t - 2 * 1536 * 512;
    bcat[t3] = (t3 < 512) ? bq[t3] : (t3 < 1024 ? bk[t3 - 512] : bv[t3 - 1024]);
  }
}

// ---------------- node embeddings: x = mean(what,action,result) --------------
__global__ void nodes_kernel(const float4* __restrict__ w, const float4* __restrict__ a,
                             const float4* __restrict__ r, float4* __restrict__ x,
                             bf16x4* __restrict__ xb) {
  size_t i = (size_t)blockIdx.x * 256 + threadIdx.x;   // 2,097,152 float4s
  float4 vw = w[i], va = a[i], vr = r[i];
  float4 v;
  v.x = (vw.x + va.x + vr.x) / 3.0f;
  v.y = (vw.y + va.y + vr.y) / 3.0f;
  v.z = (vw.z + va.z + vr.z) / 3.0f;
  v.w = (vw.w + va.w + vr.w) / 3.0f;
  x[i] = v;
  bf16x4 bv4;
  bv4[0] = (bf16)v.x; bv4[1] = (bf16)v.y; bv4[2] = (bf16)v.z; bv4[3] = (bf16)v.w;
  xb[i] = bv4;
}

// ---------------- bf16 MFMA GEMM: C = A(16384x512) * Bt^T + bias -------------
// m97 structure: 128x128 tile, BK=32, global_load_lds w16, 4 waves 2x2 of 64x64
// MODE 0: out_b[row*ldo+col] = bf16(acc + bias[col])           (QKV projection)
// MODE 1: x[row,col] += relu(acc + bias[col]); xb = bf16(x)    (hop transform)
template <int MODE>
__global__ __launch_bounds__(256)
void gemm_bt(const bf16* __restrict__ A, const bf16* __restrict__ Bt,
             const float* __restrict__ bias,
             bf16* __restrict__ out_b, int ldo,
             float* __restrict__ x, bf16* __restrict__ xb) {
  constexpr int BK = 32;
  __shared__ __align__(16) bf16 As[128 * BK];
  __shared__ __align__(16) bf16 Bs[128 * BK];
  const int tid = threadIdx.x;
  const int wave = tid >> 6, lane = tid & 63;
  const int wr = wave >> 1, wc = wave & 1;
  const int m0 = blockIdx.x * 128;
  const int n0 = blockIdx.y * 128;
  const int srow = lane >> 2;        // staging: row within 16-row chunk
  const int skg = (lane & 3) * 8;    // staging: k offset (elements)
  const int fr = lane & 15;          // fragment row/col
  const int kq = (lane >> 4) * 8;    // fragment k offset

  f32x4 acc[4][4];
#pragma unroll
  for (int i = 0; i < 4; ++i)
#pragma unroll
    for (int j = 0; j < 4; ++j) acc[i][j] = (f32x4){0.f, 0.f, 0.f, 0.f};

  for (int kt = 0; kt < 512; kt += BK) {
    __syncthreads();   // previous iter's LDS reads complete
#pragma unroll
    for (int i = 0; i < 2; ++i) {
      int c = wave * 2 + i;          // chunk 0..7 = 16 rows of 64B
      int row = c * 16 + srow;
      gload_lds16(A + (size_t)(m0 + row) * 512 + kt + skg, &As[c * 16 * BK]);
      gload_lds16(Bt + (size_t)(n0 + row) * 512 + kt + skg, &Bs[c * 16 * BK]);
    }
    __syncthreads();   // compiler drains vmcnt(0) before barrier

    bf16x8 af[4], bg[4];
#pragma unroll
    for (int i = 0; i < 4; ++i)
      af[i] = *(const bf16x8*)&As[(wr * 64 + i * 16 + fr) * BK + kq];
#pragma unroll
    for (int j = 0; j < 4; ++j)
      bg[j] = *(const bf16x8*)&Bs[(wc * 64 + j * 16 + fr) * BK + kq];
#pragma unroll
    for (int i = 0; i < 4; ++i)
#pragma unroll
      for (int j = 0; j < 4; ++j)
        acc[i][j] = __builtin_amdgcn_mfma_f32_16x16x32_bf16(af[i], bg[j], acc[i][j], 0, 0, 0);
  }

  // epilogue: C/D layout col=lane&15, row=(lane>>4)*4+reg   [m89/m91 verified]
#pragma unroll
  for (int i = 0; i < 4; ++i) {
    int grow0 = m0 + wr * 64 + i * 16 + (lane >> 4) * 4;
#pragma unroll
    for (int j = 0; j < 4; ++j) {
      int gcol = n0 + wc * 64 + j * 16 + fr;
      float bvv = bias[gcol];
#pragma unroll
      for (int q = 0; q < 4; ++q) {
        int grow = grow0 + q;
        float v = acc[i][j][q] + bvv;
        if (MODE == 0) {
          out_b[(size_t)grow * ldo + gcol] = (bf16)v;
        } else {
          v = fmaxf(v, 0.f);
          size_t idx = (size_t)grow * 512 + gcol;
          float xn = x[idx] + v;
          x[idx] = xn;
          xb[idx] = (bf16)xn;
        }
      }
    }
  }
}

// ---------------- sparse masked attention --------------------------------
// one wave per (n,b) row; QKV rows: Q at +0, K at +512, V at +1024, ld=1536
__global__ __launch_bounds__(256)
void attn_kernel(const bf16* __restrict__ QKV, bf16* __restrict__ att) {
  const int lane = threadIdx.x & 63;
  const int wid = blockIdx.x * 4 + (threadIdx.x >> 6);  // (l,b,g) ordering for K/V reuse
  const int l = wid >> 8;
  const int b = (wid >> 4) & 15;
  const int g = wid & 15;
  const int n = (g << 6) | l;
  const int r = n * 16 + b;

  bf16x8 qv = *(const bf16x8*)(QKV + (size_t)r * 1536 + lane * 8);
  float qf[8];
#pragma unroll
  for (int i = 0; i < 8; ++i) qf[i] = (float)qv[i];

  // 17 fixed neighbor slots: j<16 -> causal row ((j,l),b) [self masked], 16 -> temporal
  int rows[17];
#pragma unroll
  for (int j = 0; j < 16; ++j) rows[j] = (((j << 6) | l) << 4) | b;
  rows[16] = (l < 63) ? (r + 16) : r;

  float s[17];
#pragma unroll
  for (int j = 0; j < 17; ++j) {
    const bf16* Krow = QKV + (size_t)rows[j] * 1536 + 512;
    bf16x8 kv = *(const bf16x8*)(Krow + lane * 8);
    float p = 0.f;
#pragma unroll
    for (int i = 0; i < 8; ++i) p += qf[i] * (float)kv[i];
#pragma unroll
    for (int off = 32; off; off >>= 1) p += __shfl_xor(p, off);
    p *= 0.044194173824159216f;  // 1/sqrt(512)
    bool valid = (j < 16) ? (j != g) : (l < 63);
    s[j] = valid ? p : -1e30f;
  }

  float mx = -1e30f;
#pragma unroll
  for (int j = 0; j < 17; ++j) mx = fmaxf(mx, s[j]);
  float pr[17], sum = 0.f;
#pragma unroll
  for (int j = 0; j < 17; ++j) { pr[j] = __expf(s[j] - mx); sum += pr[j]; }
  float inv = 1.f / sum;

  float acc[8] = {0, 0, 0, 0, 0, 0, 0, 0};
#pragma unroll
  for (int j = 0; j < 17; ++j) {
    const bf16* Vrow = QKV + (size_t)rows[j] * 1536 + 1024;
    bf16x8 vv = *(const bf16x8*)(Vrow + lane * 8);
    float w = pr[j] * inv;
#pragma unroll
    for (int i = 0; i < 8; ++i) acc[i] += w * (float)vv[i];
  }
  bf16x8 ov;
#pragma unroll
  for (int i = 0; i < 8; ++i) ov[i] = (bf16)acc[i];
  *(bf16x8*)(att + (size_t)r * 512 + lane * 8) = ov;
}

// ---------------- mean over nodes + final MLP (f32, tiny) --------------------
__global__ void mean_partial(const float* __restrict__ x, float* __restrict__ partial) {
  int b = blockIdx.x, c = blockIdx.y, d = threadIdx.x;
  float s = 0.f;
  for (int n = c * 128; n < (c + 1) * 128; ++n)
    s += x[((size_t)(n * 16 + b)) * 512 + d];
  partial[(c * 16 + b) * 512 + d] = s;
}

__global__ void mean_final(const float* __restrict__ partial, float* __restrict__ agg) {
  int i = blockIdx.x * 256 + threadIdx.x;  // 8192
  float s = 0.f;
#pragma unroll
  for (int c = 0; c < 8; ++c) s += partial[c * 8192 + i];
  agg[i] = s * (1.0f / 1024.0f);
}

__global__ void mlp1(const float* __restrict__ agg, const float* __restrict__ W1,
                     const float* __restrict__ b1, float* __restrict__ hdn) {
  int t = blockIdx.x * 256 + threadIdx.x;  // 16*1024
  int b = t >> 10, o = t & 1023;
  float s = b1[o];
  for (int d = 0; d < 512; ++d) s += agg[b * 512 + d] * W1[d * 1024 + o];
  hdn[t] = fmaxf(s, 0.f);
}

__global__ void mlp2(const float* __restrict__ hdn, const float* __restrict__ W2,
                     const float* __restrict__ b2, float* __restrict__ out) {
  int t = blockIdx.x * 256 + threadIdx.x;  // 16*512
  int b = t >> 9, o = t & 511;
  float s = b2[o];
  for (int d = 0; d < 1024; ++d) s += hdn[b * 1024 + d] * W2[d * 512 + o];
  out[t] = s;
}

// ---------------- launch -----------------------------------------------------
extern "C" void kernel_launch(void* const* d_in, const int* in_sizes, int n_in,
                              void* d_out, int out_size, void* d_ws, size_t ws_size,
                              hipStream_t stream) {
  const float* what   = (const float*)d_in[0];
  const float* action = (const float*)d_in[1];
  const float* result = (const float*)d_in[2];
  const float* Wq = (const float*)d_in[3];
  const float* bq = (const float*)d_in[4];
  const float* Wk = (const float*)d_in[5];
  const float* bk = (const float*)d_in[6];
  const float* Wv = (const float*)d_in[7];
  const float* bv = (const float*)d_in[8];
  const float* Whop = (const float*)d_in[9];
  const float* bhop = (const float*)d_in[10];
  const float* W1 = (const float*)d_in[11];
  const float* b1 = (const float*)d_in[12];
  const float* W2 = (const float*)d_in[13];
  const float* b2 = (const float*)d_in[14];
  float* out = (float*)d_out;

  char* ws = (char*)d_ws;
  float* x      = (float*)(ws + 0);              // 33,554,432 B
  bf16*  xb     = (bf16*)(ws + 33554432);        // 16,777,216 B
  bf16*  QKV    = (bf16*)(ws + 50331648);        // 50,331,648 B (ld=1536)
  bf16*  att    = (bf16*)(ws + 100663296);       // 16,777,216 B
  bf16*  WtQKV  = (bf16*)(ws + 117440512);       //  1,572,864 B
  bf16*  WtHop  = (bf16*)(ws + 119013376);       //  1,572,864 B
  float* bcat   = (float*)(ws + 120586240);      //      6,144 B
  float* partial= (float*)(ws + 120592384);      //    262,144 B
  float* agg    = (float*)(ws + 120854528);      //     32,768 B
  float* hdn    = (float*)(ws + 120887296);      //     65,536 B

  prep_weights<<<6150, 256, 0, stream>>>(Wq, Wk, Wv, Whop, bq, bk, bv, WtQKV, WtHop, bcat);
  nodes_kernel<<<8192, 256, 0, stream>>>((const float4*)what, (const float4*)action,
                                         (const float4*)result, (float4*)x, (bf16x4*)xb);
  for (int h = 0; h < 3; ++h) {
    gemm_bt<0><<<dim3(128, 12), 256, 0, stream>>>(xb, WtQKV, bcat, QKV, 1536, nullptr, nullptr);
    attn_kernel<<<4096, 256, 0, stream>>>(QKV, att);
    gemm_bt<1><<<dim3(128, 4), 256, 0, stream>>>(att, WtHop + h * 262144, bhop + h * 512,
                                                 nullptr, 0, x, xb);
  }
  mean_partial<<<dim3(16, 8), 512, 0, stream>>>(x, partial);
  mean_final<<<32, 256, 0, stream>>>(partial, agg);
  mlp1<<<64, 256, 0, stream>>>(agg, W1, b1, hdn);
  mlp2<<<32, 256, 0, stream>>>(hdn, W2, b2, out);
}

// Round 2
// 350.225 us; speedup vs baseline: 1.2244x; 1.2244x over previous
//
#include <hip/hip_runtime.h>
#include <stdint.h>

// DreamGraphReasoner on MI355X (gfx950)
// x layout: (N, B, D) row-major, row r = n*B + b  (== input (G,L,B,D) flat order)
// Sparse attention: node n=(g,l) attends to {(g',l): g'!=g} U {(g,l+1) if l<63}

#define Gd 16
#define Ld 64
#define Bb 16
#define Dd 512
#define NN 1024   // Gd*Ld
#define MM 16384  // NN*Bb

typedef __bf16 bf16;
typedef __bf16 bf16x8 __attribute__((ext_vector_type(8)));
typedef __bf16 bf16x4 __attribute__((ext_vector_type(4)));
typedef float  f32x4  __attribute__((ext_vector_type(4)));

__device__ __forceinline__ void gload_lds16(const void* g, void* l) {
  __builtin_amdgcn_global_load_lds(
      (__attribute__((address_space(1))) void*)(size_t)(g),
      (__attribute__((address_space(3))) void*)(l), 16, 0, 0);
}

// ---------------- weight prep: bf16 transpose + QKV bias concat + f32 W1t/W2t
__global__ void prep_weights(const float* __restrict__ Wq, const float* __restrict__ Wk,
                             const float* __restrict__ Wv, const float* __restrict__ Whop,
                             const float* __restrict__ bq, const float* __restrict__ bk,
                             const float* __restrict__ bv,
                             const float* __restrict__ W1, const float* __restrict__ W2,
                             bf16* __restrict__ WtQKV, bf16* __restrict__ WtHop,
                             float* __restrict__ bcat,
                             float* __restrict__ W1t, float* __restrict__ W2t) {
  int t = blockIdx.x * 256 + threadIdx.x;
  if (t < 1536 * 512) {                 // WtQKV[col][k] = W*[k][col&511]
    int col = t >> 9, k = t & 511;
    const float* W = (col < 512) ? Wq : (col < 1024 ? Wk : Wv);
    WtQKV[t] = (bf16)W[k * 512 + (col & 511)];
  } else if (t < 2 * 1536 * 512) {      // WtHop[h][col][k] = Whop[h][k][col]
    int t2 = t - 1536 * 512;
    int h = t2 >> 18, rem = t2 & 262143;
    int col = rem >> 9, k = rem & 511;
    WtHop[t2] = (bf16)Whop[h * 262144 + k * 512 + col];
  } else if (t < 2 * 1536 * 512 + 1536) {
    int t3 = t - 2 * 1536 * 512;
    bcat[t3] = (t3 < 512) ? bq[t3] : (t3 < 1024 ? bk[t3 - 512] : bv[t3 - 1024]);
  } else if (t < 2 * 1536 * 512 + 1536 + 524288) {   // W1t[o][d] = W1[d][o]
    int t4 = t - (2 * 1536 * 512 + 1536);
    int o = t4 >> 9, d = t4 & 511;
    W1t[t4] = W1[d * 1024 + o];
  } else if (t < 2 * 1536 * 512 + 1536 + 2 * 524288) { // W2t[o][d] = W2[d][o]
    int t5 = t - (2 * 1536 * 512 + 1536 + 524288);
    int o = t5 >> 10, d = t5 & 1023;
    W2t[t5] = W2[d * 512 + o];
  }
}

// ---------------- node embeddings: x = mean(what,action,result) --------------
__global__ void nodes_kernel(const float4* __restrict__ w, const float4* __restrict__ a,
                             const float4* __restrict__ r, float4* __restrict__ x,
                             bf16x4* __restrict__ xb) {
  size_t i = (size_t)blockIdx.x * 256 + threadIdx.x;   // 2,097,152 float4s
  float4 vw = w[i], va = a[i], vr = r[i];
  float4 v;
  v.x = (vw.x + va.x + vr.x) / 3.0f;
  v.y = (vw.y + va.y + vr.y) / 3.0f;
  v.z = (vw.z + va.z + vr.z) / 3.0f;
  v.w = (vw.w + va.w + vr.w) / 3.0f;
  x[i] = v;
  bf16x4 bv4;
  bv4[0] = (bf16)v.x; bv4[1] = (bf16)v.y; bv4[2] = (bf16)v.z; bv4[3] = (bf16)v.w;
  xb[i] = bv4;
}

// ---------------- bf16 MFMA GEMM: C = A(16384x512) * Bt^T + bias -------------
template <int MODE>
__global__ __launch_bounds__(256)
void gemm_bt(const bf16* __restrict__ A, const bf16* __restrict__ Bt,
             const float* __restrict__ bias,
             bf16* __restrict__ out_b, int ldo,
             float* __restrict__ x, bf16* __restrict__ xb) {
  constexpr int BK = 32;
  __shared__ __align__(16) bf16 As[128 * BK];
  __shared__ __align__(16) bf16 Bs[128 * BK];
  const int tid = threadIdx.x;
  const int wave = tid >> 6, lane = tid & 63;
  const int wr = wave >> 1, wc = wave & 1;
  const int m0 = blockIdx.x * 128;
  const int n0 = blockIdx.y * 128;
  const int srow = lane >> 2;
  const int skg = (lane & 3) * 8;
  const int fr = lane & 15;
  const int kq = (lane >> 4) * 8;

  f32x4 acc[4][4];
#pragma unroll
  for (int i = 0; i < 4; ++i)
#pragma unroll
    for (int j = 0; j < 4; ++j) acc[i][j] = (f32x4){0.f, 0.f, 0.f, 0.f};

  for (int kt = 0; kt < 512; kt += BK) {
    __syncthreads();
#pragma unroll
    for (int i = 0; i < 2; ++i) {
      int c = wave * 2 + i;
      int row = c * 16 + srow;
      gload_lds16(A + (size_t)(m0 + row) * 512 + kt + skg, &As[c * 16 * BK]);
      gload_lds16(Bt + (size_t)(n0 + row) * 512 + kt + skg, &Bs[c * 16 * BK]);
    }
    __syncthreads();

    bf16x8 af[4], bg[4];
#pragma unroll
    for (int i = 0; i < 4; ++i)
      af[i] = *(const bf16x8*)&As[(wr * 64 + i * 16 + fr) * BK + kq];
#pragma unroll
    for (int j = 0; j < 4; ++j)
      bg[j] = *(const bf16x8*)&Bs[(wc * 64 + j * 16 + fr) * BK + kq];
#pragma unroll
    for (int i = 0; i < 4; ++i)
#pragma unroll
      for (int j = 0; j < 4; ++j)
        acc[i][j] = __builtin_amdgcn_mfma_f32_16x16x32_bf16(af[i], bg[j], acc[i][j], 0, 0, 0);
  }

#pragma unroll
  for (int i = 0; i < 4; ++i) {
    int grow0 = m0 + wr * 64 + i * 16 + (lane >> 4) * 4;
#pragma unroll
    for (int j = 0; j < 4; ++j) {
      int gcol = n0 + wc * 64 + j * 16 + fr;
      float bvv = bias[gcol];
#pragma unroll
      for (int q = 0; q < 4; ++q) {
        int grow = grow0 + q;
        float v = acc[i][j][q] + bvv;
        if (MODE == 0) {
          out_b[(size_t)grow * ldo + gcol] = (bf16)v;
        } else {
          v = fmaxf(v, 0.f);
          size_t idx = (size_t)grow * 512 + gcol;
          float xn = x[idx] + v;
          x[idx] = xn;
          xb[idx] = (bf16)xn;
        }
      }
    }
  }
}

// ---------------- sparse masked attention --------------------------------
__global__ __launch_bounds__(256)
void attn_kernel(const bf16* __restrict__ QKV, bf16* __restrict__ att) {
  const int lane = threadIdx.x & 63;
  const int wid = blockIdx.x * 4 + (threadIdx.x >> 6);  // (l,b,g) ordering
  const int l = wid >> 8;
  const int b = (wid >> 4) & 15;
  const int g = wid & 15;
  const int n = (g << 6) | l;
  const int r = n * 16 + b;

  bf16x8 qv = *(const bf16x8*)(QKV + (size_t)r * 1536 + lane * 8);
  float qf[8];
#pragma unroll
  for (int i = 0; i < 8; ++i) qf[i] = (float)qv[i];

  int rows[17];
#pragma unroll
  for (int j = 0; j < 16; ++j) rows[j] = (((j << 6) | l) << 4) | b;
  rows[16] = (l < 63) ? (r + 16) : r;

  float s[17];
#pragma unroll
  for (int j = 0; j < 17; ++j) {
    const bf16* Krow = QKV + (size_t)rows[j] * 1536 + 512;
    bf16x8 kv = *(const bf16x8*)(Krow + lane * 8);
    float p = 0.f;
#pragma unroll
    for (int i = 0; i < 8; ++i) p += qf[i] * (float)kv[i];
#pragma unroll
    for (int off = 32; off; off >>= 1) p += __shfl_xor(p, off);
    p *= 0.044194173824159216f;  // 1/sqrt(512)
    bool valid = (j < 16) ? (j != g) : (l < 63);
    s[j] = valid ? p : -1e30f;
  }

  float mx = -1e30f;
#pragma unroll
  for (int j = 0; j < 17; ++j) mx = fmaxf(mx, s[j]);
  float pr[17], sum = 0.f;
#pragma unroll
  for (int j = 0; j < 17; ++j) { pr[j] = __expf(s[j] - mx); sum += pr[j]; }
  float inv = 1.f / sum;

  float acc[8] = {0, 0, 0, 0, 0, 0, 0, 0};
#pragma unroll
  for (int j = 0; j < 17; ++j) {
    const bf16* Vrow = QKV + (size_t)rows[j] * 1536 + 1024;
    bf16x8 vv = *(const bf16x8*)(Vrow + lane * 8);
    float w = pr[j] * inv;
#pragma unroll
    for (int i = 0; i < 8; ++i) acc[i] += w * (float)vv[i];
  }
  bf16x8 ov;
#pragma unroll
  for (int i = 0; i < 8; ++i) ov[i] = (bf16)acc[i];
  *(bf16x8*)(att + (size_t)r * 512 + lane * 8) = ov;
}

// ---------------- mean over nodes (two-phase, 512 blocks) --------------------
__global__ void mean_partial(const float* __restrict__ x, float* __restrict__ partial) {
  int b = blockIdx.x, c = blockIdx.y, d = threadIdx.x;
  float s = 0.f;
#pragma unroll 4
  for (int n = c * 32; n < (c + 1) * 32; ++n)
    s += x[((size_t)(n * 16 + b)) * 512 + d];
  partial[(c * 16 + b) * 512 + d] = s;
}

__global__ void mean_final(const float* __restrict__ partial, float* __restrict__ agg) {
  int i = blockIdx.x * 256 + threadIdx.x;  // 8192
  float s = 0.f;
#pragma unroll
  for (int c = 0; c < 32; ++c) s += partial[c * 8192 + i];
  agg[i] = s * (1.0f / 1024.0f);
}

// ---------------- final MLP: wave-per-output-column, lanes=(b, quarter) ------
// mlp1: hdn[b][o] = relu(b1[o] + sum_d agg[b][d] * W1t[o][d]),  o<1024, d<512
__global__ __launch_bounds__(256)
void mlp1(const float* __restrict__ agg, const float* __restrict__ W1t,
          const float* __restrict__ b1, float* __restrict__ hdn) {
  const int lane = threadIdx.x & 63;
  const int o = blockIdx.x * 4 + (threadIdx.x >> 6);   // 256 blocks * 4 waves
  const int b = lane & 15, q = lane >> 4;              // quarter of d-range
  const float4* wp = (const float4*)(W1t + o * 512 + q * 128);
  const float4* ap = (const float4*)(agg + b * 512 + q * 128);
  float acc = 0.f;
#pragma unroll
  for (int i = 0; i < 32; ++i) {
    float4 w = wp[i], a = ap[i];
    acc += w.x * a.x + w.y * a.y + w.z * a.z + w.w * a.w;
  }
  acc += __shfl_xor(acc, 16);
  acc += __shfl_xor(acc, 32);
  if (lane < 16) hdn[b * 1024 + o] = fmaxf(acc + b1[o], 0.f);
}

// mlp2: out[b][o] = b2[o] + sum_d hdn[b][d] * W2t[o][d],  o<512, d<1024
__global__ __launch_bounds__(256)
void mlp2(const float* __restrict__ hdn, const float* __restrict__ W2t,
          const float* __restrict__ b2, float* __restrict__ out) {
  const int lane = threadIdx.x & 63;
  const int o = blockIdx.x * 4 + (threadIdx.x >> 6);   // 128 blocks * 4 waves
  const int b = lane & 15, q = lane >> 4;
  const float4* wp = (const float4*)(W2t + o * 1024 + q * 256);
  const float4* hp = (const float4*)(hdn + b * 1024 + q * 256);
  float acc = 0.f;
#pragma unroll
  for (int i = 0; i < 64; ++i) {
    float4 w = wp[i], h = hp[i];
    acc += w.x * h.x + w.y * h.y + w.z * h.z + w.w * h.w;
  }
  acc += __shfl_xor(acc, 16);
  acc += __shfl_xor(acc, 32);
  if (lane < 16) out[b * 512 + o] = acc + b2[o];
}

// ---------------- launch -----------------------------------------------------
extern "C" void kernel_launch(void* const* d_in, const int* in_sizes, int n_in,
                              void* d_out, int out_size, void* d_ws, size_t ws_size,
                              hipStream_t stream) {
  const float* what   = (const float*)d_in[0];
  const float* action = (const float*)d_in[1];
  const float* result = (const float*)d_in[2];
  const float* Wq = (const float*)d_in[3];
  const float* bq = (const float*)d_in[4];
  const float* Wk = (const float*)d_in[5];
  const float* bk = (const float*)d_in[6];
  const float* Wv = (const float*)d_in[7];
  const float* bv = (const float*)d_in[8];
  const float* Whop = (const float*)d_in[9];
  const float* bhop = (const float*)d_in[10];
  const float* W1 = (const float*)d_in[11];
  const float* b1 = (const float*)d_in[12];
  const float* W2 = (const float*)d_in[13];
  const float* b2 = (const float*)d_in[14];
  float* out = (float*)d_out;

  char* ws = (char*)d_ws;
  float* x      = (float*)(ws + 0);              // 33,554,432 B
  bf16*  xb     = (bf16*)(ws + 33554432);        // 16,777,216 B
  bf16*  QKV    = (bf16*)(ws + 50331648);        // 50,331,648 B (ld=1536)
  bf16*  att    = (bf16*)(ws + 100663296);       // 16,777,216 B
  bf16*  WtQKV  = (bf16*)(ws + 117440512);       //  1,572,864 B
  bf16*  WtHop  = (bf16*)(ws + 119013376);       //  1,572,864 B
  float* bcat   = (float*)(ws + 120586240);      //      6,144 B
  float* W1t    = (float*)(ws + 120592384);      //  2,097,152 B
  float* W2t    = (float*)(ws + 122689536);      //  2,097,152 B
  float* partial= (float*)(ws + 124786688);      //  1,048,576 B
  float* agg    = (float*)(ws + 125835264);      //     32,768 B
  float* hdn    = (float*)(ws + 125868032);      //     65,536 B

  prep_weights<<<10246, 256, 0, stream>>>(Wq, Wk, Wv, Whop, bq, bk, bv, W1, W2,
                                          WtQKV, WtHop, bcat, W1t, W2t);
  nodes_kernel<<<8192, 256, 0, stream>>>((const float4*)what, (const float4*)action,
                                         (const float4*)result, (float4*)x, (bf16x4*)xb);
  for (int h = 0; h < 3; ++h) {
    gemm_bt<0><<<dim3(128, 12), 256, 0, stream>>>(xb, WtQKV, bcat, QKV, 1536, nullptr, nullptr);
    attn_kernel<<<4096, 256, 0, stream>>>(QKV, att);
    gemm_bt<1><<<dim3(128, 4), 256, 0, stream>>>(att, WtHop + h * 262144, bhop + h * 512,
                                                 nullptr, 0, x, xb);
  }
  mean_partial<<<dim3(16, 32), 512, 0, stream>>>(x, partial);
  mean_final<<<32, 256, 0, stream>>>(partial, agg);
  mlp1<<<256, 256, 0, stream>>>(agg, W1t, b1, hdn);
  mlp2<<<128, 256, 0, stream>>>(hdn, W2t, b2, out);
}